// Round 8
// baseline (969.796 us; speedup 1.0000x reference)
//
#include <hip/hip_runtime.h>
#include <hip/hip_cooperative_groups.h>
#include <math.h>

namespace cg = cooperative_groups;

// B=4096, N=200, D=128, V=100000
//   h = gelu(x @ W_mu + b_mu);  logits[b,n] = dot(h[b], emb[cand[b,n]]) + mu_bias[cand[b,n]]
//
// R4 (2 dispatches, direct gather): wall 157.5us; gather 64us, 199MB post-L2 @3.3TB/s.
// R5 (9 dispatches, vocab-binned): wall 246us — FETCH fell to 49MB (mechanism works!)
//     but 8.2 pairs/wave = latency-bound, and ~11us/dispatch launch overhead.
// R7: ONE cooperative dispatch: bucket-sort pairs (bucket = c>>4 = 16 rows = 8KB emb,
//     L1-resident), then pair-parallel dot — R5's traffic with R4's parallel shape.

#define BDIM 4096
#define NCAND 200
#define DDIM 128
#define VOCAB 100000
#define NPAIRS (BDIM * NCAND)        // 819200
#define SHIFT 4
#define NBUCK (VOCAB >> SHIFT)       // 6250
#define NWU (NPAIRS / 64)            // 12800 wave-units

typedef unsigned int u32;

// ---------------- single fused cooperative kernel ----------------
__global__ __launch_bounds__(256, 8) void fused_all(
    const float* __restrict__ x, const int* __restrict__ cand,
    const float* __restrict__ W, const float* __restrict__ bvec,
    const float* __restrict__ bias, const float* __restrict__ emb,
    float* __restrict__ out, float* __restrict__ h,
    u32* __restrict__ cnt, u32* __restrict__ pairs) {
  cg::grid_group grid = cg::this_grid();
  __shared__ float smem[256]; // 1KB: x-rows in P1, scan array in P3
  const int t = threadIdx.x;
  const int nthr = gridDim.x * 256;
  const int gtid = blockIdx.x * 256 + t;

  // ---- P1: zero bucket counters + GELU head (1 output/thread/unit) ----
  for (int i = gtid; i < NBUCK; i += nthr) cnt[i] = 0u;
  for (int u = blockIdx.x; u < BDIM / 2; u += gridDim.x) {
    const int b0 = u * 2; // two x-rows per unit
    {
      const float4* xg = reinterpret_cast<const float4*>(x + (size_t)b0 * DDIM);
      if (t < 64) reinterpret_cast<float4*>(smem)[t] = xg[t];
    }
    __syncthreads();
    const int col = t & 127;
    const int rp = t >> 7;
    float acc = 0.f;
#pragma unroll 8
    for (int k = 0; k < DDIM; ++k)
      acc = fmaf(smem[rp * DDIM + k], W[k * DDIM + col], acc);
    acc += bvec[col];
    h[(size_t)(b0 + rp) * DDIM + col] =
        0.5f * acc * (1.0f + erff(acc * 0.70710678118654752f));
    __syncthreads();
  }
  grid.sync();

  // ---- P2: histogram into 6250 buckets ----
  for (int i = gtid; i < NPAIRS; i += nthr)
    atomicAdd(&cnt[((u32)cand[i]) >> SHIFT], 1u);
  grid.sync();

  // ---- P3: exclusive scan of 6250 counters (block 0), cnt becomes cursors ----
  if (blockIdx.x == 0) {
    u32* sh = reinterpret_cast<u32*>(smem);
    const int base = t * 25; // 256*25 = 6400 >= 6250
    u32 s = 0;
    for (int k = 0; k < 25; ++k) {
      const int i = base + k;
      if (i < NBUCK) s += cnt[i];
    }
    sh[t] = s;
    __syncthreads();
    for (int off = 1; off < 256; off <<= 1) {
      const u32 v = (t >= off) ? sh[t - off] : 0u;
      __syncthreads();
      sh[t] += v;
      __syncthreads();
    }
    u32 excl = sh[t] - s;
    for (int k = 0; k < 25; ++k) {
      const int i = base + k;
      if (i < NBUCK) {
        const u32 v = cnt[i];
        cnt[i] = excl;
        excl += v;
      }
    }
  }
  grid.sync();

  // ---- P4: scatter pair indices into bucket order ----
  for (int i = gtid; i < NPAIRS; i += nthr) {
    const u32 pos = atomicAdd(&cnt[((u32)cand[i]) >> SHIFT], 1u);
    pairs[pos] = (u32)i;
  }
  grid.sync();

  // ---- P5: pair-parallel dot over bucket-sorted pairs ----
  const int lane = t & 63;
  const int l16 = lane & 15;
  const int grp = lane >> 4;
  const int gwave = gtid >> 6;
  const int nwaves = nthr >> 6;
  for (int wu = gwave; wu < NWU; wu += nwaves) {
    const u32 pidx = pairs[(u32)wu * 64u + (u32)lane]; // coalesced
    const int c = cand[pidx];                          // 4B gather, L2-resident
    const float bi = bias[c];                          // 4B gather, L2-resident
#pragma unroll 4
    for (int i2 = 0; i2 < 16; ++i2) {
      const int slot = i2 * 4 + grp;
      const u32 idx_s = (u32)__shfl((int)pidx, slot);
      const int c_s = __shfl(c, slot);
      const float4* ev = reinterpret_cast<const float4*>(emb + (size_t)c_s * DDIM);
      const float4 e1 = ev[l16];
      const float4 e2 = ev[l16 + 16];
      const u32 b = idx_s / 200u; // magic-mul division
      const float4* hv = reinterpret_cast<const float4*>(h + (size_t)b * DDIM);
      const float4 h1 = hv[l16];
      const float4 h2 = hv[l16 + 16];
      float acc = e1.x * h1.x;
      acc = fmaf(e1.y, h1.y, acc);
      acc = fmaf(e1.z, h1.z, acc);
      acc = fmaf(e1.w, h1.w, acc);
      acc = fmaf(e2.x, h2.x, acc);
      acc = fmaf(e2.y, h2.y, acc);
      acc = fmaf(e2.z, h2.z, acc);
      acc = fmaf(e2.w, h2.w, acc);
      acc += __shfl_xor(acc, 1);
      acc += __shfl_xor(acc, 2);
      acc += __shfl_xor(acc, 4);
      acc += __shfl_xor(acc, 8);
      const float bs = __shfl(bi, slot);
      if (l16 == 0) out[idx_s] = acc + bs;
    }
  }
}

// ---------------- fallback path (R4-proven, 2 dispatches) ----------------
__global__ __launch_bounds__(256) void gelu_head_kernel(
    const float* __restrict__ x, const float* __restrict__ W,
    const float* __restrict__ bvec, float* __restrict__ h) {
  __shared__ float xs[8][DDIM];
  const int b0 = blockIdx.x * 8;
  const int t = threadIdx.x;
  {
    const float4* xg = reinterpret_cast<const float4*>(x + (size_t)b0 * DDIM);
    reinterpret_cast<float4*>(&xs[0][0])[t] = xg[t];
  }
  __syncthreads();
  const int col = t & 127;
  const int rp = t >> 7;
  float acc0 = 0.f, acc1 = 0.f, acc2 = 0.f, acc3 = 0.f;
#pragma unroll 8
  for (int k = 0; k < DDIM; ++k) {
    const float w = W[k * DDIM + col];
    acc0 = fmaf(xs[rp + 0][k], w, acc0);
    acc1 = fmaf(xs[rp + 2][k], w, acc1);
    acc2 = fmaf(xs[rp + 4][k], w, acc2);
    acc3 = fmaf(xs[rp + 6][k], w, acc3);
  }
  const float bb = bvec[col];
  float v[4] = {acc0 + bb, acc1 + bb, acc2 + bb, acc3 + bb};
#pragma unroll
  for (int r = 0; r < 4; ++r) {
    const float u = v[r];
    h[(size_t)(b0 + rp + 2 * r) * DDIM + col] =
        0.5f * u * (1.0f + erff(u * 0.70710678118654752f));
  }
}

__global__ __launch_bounds__(256) void gather_dot_kernel(
    const float* __restrict__ h, const int* __restrict__ cand,
    const float* __restrict__ bias, const float* __restrict__ emb,
    float* __restrict__ out) {
  const int wave = (blockIdx.x * 256 + threadIdx.x) >> 6;
  const int lane = threadIdx.x & 63;
  const int b = wave >> 1;
  const int half = wave & 1;
  const int l16 = lane & 15;
  const int grp = lane >> 4;
  const float4* hv = reinterpret_cast<const float4*>(h + (size_t)b * DDIM);
  const float4 h1 = hv[l16];
  const float4 h2 = hv[l16 + 16];
  const int nstart = half * 100;
  const int nend = nstart + 100;
  const int rowbase = b * NCAND;
  for (int n0 = nstart; n0 < nend; n0 += 64) {
    const int nseg = min(64, nend - n0);
    int ci = 0;
    float bv = 0.f;
    if (lane < nseg) {
      ci = cand[rowbase + n0 + lane];
      bv = bias[ci];
    }
    const int iters = nseg >> 2;
#pragma unroll 4
    for (int i = 0; i < iters; ++i) {
      const int slot = i * 4 + grp;
      const int c = __shfl(ci, slot);
      const float4* ev = reinterpret_cast<const float4*>(emb + (size_t)c * DDIM);
      const float4 v1 = ev[l16];
      const float4 v2 = ev[l16 + 16];
      float acc = v1.x * h1.x;
      acc = fmaf(v1.y, h1.y, acc);
      acc = fmaf(v1.z, h1.z, acc);
      acc = fmaf(v1.w, h1.w, acc);
      acc = fmaf(v2.x, h2.x, acc);
      acc = fmaf(v2.y, h2.y, acc);
      acc = fmaf(v2.z, h2.z, acc);
      acc = fmaf(v2.w, h2.w, acc);
      acc += __shfl_xor(acc, 1);
      acc += __shfl_xor(acc, 2);
      acc += __shfl_xor(acc, 4);
      acc += __shfl_xor(acc, 8);
      const float bslot = __shfl(bv, slot);
      if (l16 == 0) out[rowbase + n0 + slot] = acc + bslot;
    }
  }
}

extern "C" void kernel_launch(void* const* d_in, const int* in_sizes, int n_in,
                              void* d_out, int out_size, void* d_ws, size_t ws_size,
                              hipStream_t stream) {
  const float* x = (const float*)d_in[0];
  const int* candidates = (const int*)d_in[1];
  const float* W_mu = (const float*)d_in[2];
  const float* b_mu = (const float*)d_in[3];
  const float* mu_bias = (const float*)d_in[4];
  const float* emb_table = (const float*)d_in[5];
  float* out = (float*)d_out;

  char* ws = (char*)d_ws;
  size_t off = 0;
  float* h = (float*)(ws + off);
  off += (size_t)BDIM * DDIM * 4;                 // 2,097,152
  u32* cnt = (u32*)(ws + off);
  off += ((NBUCK * 4 + 255) / 256) * 256;         // 25,088
  u32* pairs = (u32*)(ws + off);
  off += (size_t)NPAIRS * 4;                      // 3,276,800
  const size_t needed = off;                      // ~5.4 MB

  bool done = false;
  if (ws_size >= needed) {
    void* args[] = {(void*)&x,        (void*)&candidates, (void*)&W_mu,
                    (void*)&b_mu,     (void*)&mu_bias,    (void*)&emb_table,
                    (void*)&out,      (void*)&h,          (void*)&cnt,
                    (void*)&pairs};
    // 1600 blocks: 6400 waves -> exactly 2 wave-units each in P5 (no imbalance).
    hipError_t err = hipLaunchCooperativeKernel((const void*)fused_all, dim3(1600),
                                                dim3(256), args, 0, stream);
    if (err != hipSuccess) {
      err = hipLaunchCooperativeKernel((const void*)fused_all, dim3(1024),
                                       dim3(256), args, 0, stream);
    }
    done = (err == hipSuccess);
    if (!done) (void)hipGetLastError(); // clear sticky error before fallback
  }

  if (!done) {
    gelu_head_kernel<<<BDIM / 8, 256, 0, stream>>>(x, W_mu, b_mu, h);
    gather_dot_kernel<<<(BDIM * 2) / 4, 256, 0, stream>>>(h, candidates, mu_bias,
                                                          emb_table, out);
  }
}

// Round 12
// 153.655 us; speedup vs baseline: 6.3115x; 6.3115x over previous
//
#include <hip/hip_runtime.h>
#include <math.h>

// B=4096, N=200, D=128, V=100000
//   h = gelu(x @ W_mu + b_mu);  logits[b,n] = dot(h[b], emb[cand[b,n]]) + mu_bias[cand[b,n]]
//
// History:
//  R4 (2 dispatches, direct gather): wall 157.5us; dot kernel 64us @3.3TB/s gather.
//  R5 (9 dispatches, vocab-binned):  wall 246us — latency-bound + dispatch overhead.
//  R8 (1 cooperative dispatch):      wall 970us — grid.sync() kills all XCD L2
//      residency (VALU 1.3%, 330GB/s). Grid-wide sync is poison on 8-XCD MI355X.
//  Overhead model: wall ~= 65us fixed + 11us/dispatch + sum(kernels).
//  R9..R11: ONE plain dispatch. Each block computes h for its own 2 rows (W
//      streamed from L2, ~64KB/block), then runs the R4-proven gather-dot.

#define BDIM 4096
#define NCAND 200
#define DDIM 128

__global__ __launch_bounds__(256) void fused_head_dot(
    const float* __restrict__ x, const int* __restrict__ cand,
    const float* __restrict__ W, const float* __restrict__ bvec,
    const float* __restrict__ bias, const float* __restrict__ emb,
    float* __restrict__ out) {
  __shared__ float xs[2][DDIM];
  __shared__ float hs[2][DDIM];
  const int t = threadIdx.x;
  const int b0 = blockIdx.x * 2; // two batch rows per block

  // ---- phase 1: h[b0..b0+1] = gelu(x @ W + b), block-local ----
  if (t < 64) {
    reinterpret_cast<float4*>(&xs[0][0])[t] =
        reinterpret_cast<const float4*>(x + (size_t)b0 * DDIM)[t];
  }
  __syncthreads();
  {
    const int col = t & 127;
    const int rr = t >> 7; // row 0 or 1
    float acc = 0.f;
#pragma unroll 8
    for (int k = 0; k < DDIM; ++k)
      acc = fmaf(xs[rr][k], W[k * DDIM + col], acc); // W: coalesced, L2-hot
    acc += bvec[col];
    hs[rr][col] = 0.5f * acc * (1.0f + erff(acc * 0.70710678118654752f));
  }
  __syncthreads();

  // ---- phase 2: gather-dot (R4-proven structure) ----
  // wave w (0..3): row r = w>>1, half = w&1 (candidates [100*half, 100*half+100))
  const int wv = t >> 6;
  const int lane = t & 63;
  const int l16 = lane & 15;
  const int grp = lane >> 4;
  const int r = wv >> 1;
  const int half = wv & 1;
  const int b = b0 + r;

  const float4 h1 = reinterpret_cast<const float4*>(&hs[r][0])[l16];
  const float4 h2 = reinterpret_cast<const float4*>(&hs[r][0])[l16 + 16];

  const int nstart = half * 100;
  const int nend = nstart + 100;
  const int rowbase = b * NCAND;

  for (int n0 = nstart; n0 < nend; n0 += 64) {
    const int nseg = min(64, nend - n0); // 64 then 36 (both %4==0)
    int ci = 0;
    float bv = 0.f;
    if (lane < nseg) {
      ci = cand[rowbase + n0 + lane];
      bv = bias[ci]; // 400KB table, L2/L3-resident
    }
    const int iters = nseg >> 2;
#pragma unroll 4
    for (int i = 0; i < iters; ++i) {
      const int slot = i * 4 + grp;
      const int c = __shfl(ci, slot);
      const float4* ev = reinterpret_cast<const float4*>(emb + (size_t)c * DDIM);
      const float4 v1 = ev[l16];
      const float4 v2 = ev[l16 + 16];
      float acc = v1.x * h1.x;
      acc = fmaf(v1.y, h1.y, acc);
      acc = fmaf(v1.z, h1.z, acc);
      acc = fmaf(v1.w, h1.w, acc);
      acc = fmaf(v2.x, h2.x, acc);
      acc = fmaf(v2.y, h2.y, acc);
      acc = fmaf(v2.z, h2.z, acc);
      acc = fmaf(v2.w, h2.w, acc);
      // 16-lane butterfly (shared across the 4 groups)
      acc += __shfl_xor(acc, 1);
      acc += __shfl_xor(acc, 2);
      acc += __shfl_xor(acc, 4);
      acc += __shfl_xor(acc, 8);
      const float bslot = __shfl(bv, slot);
      if (l16 == 0) out[rowbase + n0 + slot] = acc + bslot;
    }
  }
}

extern "C" void kernel_launch(void* const* d_in, const int* in_sizes, int n_in,
                              void* d_out, int out_size, void* d_ws, size_t ws_size,
                              hipStream_t stream) {
  const float* x = (const float*)d_in[0];
  const int* candidates = (const int*)d_in[1];
  const float* W_mu = (const float*)d_in[2];
  const float* b_mu = (const float*)d_in[3];
  const float* mu_bias = (const float*)d_in[4];
  const float* emb_table = (const float*)d_in[5];
  float* out = (float*)d_out;

  fused_head_dot<<<BDIM / 2, 256, 0, stream>>>(x, candidates, W_mu, b_mu,
                                               mu_bias, emb_table, out);
}